// Round 11
// baseline (230.308 us; speedup 1.0000x reference)
//
#include <hip/hip_runtime.h>
#include <hip/hip_fp16.h>

#define N_NODES 100000
#define N_EDGES 1600000
#define NUM_G   4096
#define HID     128
#define F_IN    11
#define F_PAD   16
#define F_OUT   19

#define NB      256                  // dst buckets
#define KPB     391                  // nodes per bucket: 256*391 = 100096 >= 100000
#define BCAP    8192                 // padded capacity per bucket (max count ~6600)
#define GCAP    1024                 // padded ewp capacity per graph (max ~790)
#define P01_EPB 2048                 // edges per block in P1
#define NBLK_E  782                  // edge blocks in P1 = ceil(1.6M/2048)
#define NGBB    16                   // gb blocks in P1 (16*256 = 4096 graphs)
#define NREG    8                    // src regions (XCD shards)
#define REGW    12500                // nodes per region
#define GPB     4                    // graphs per pool_gather block (8 groups/graph)
#define NAGG    782                  // agg blocks = ceil(100000/128)
#define CH_G    8                    // graphs per combine_head block

// cw.x layout: [dstLocal:9 | src:17]  (src < 2^17 = 131072 > 100000; dl < 391 < 512)
#define SRC_MASK 0x1FFFFu

// ---------------- helpers ----------------
__device__ inline void acc_row_f16(float* acc, uint4 u, float w) {
    const __half2* hp = (const __half2*)&u;
#pragma unroll
    for (int i = 0; i < 4; ++i) {
        acc[2 * i]     += __half2float(__low2half(hp[i]))  * w;
        acc[2 * i + 1] += __half2float(__high2half(hp[i])) * w;
    }
}
__device__ inline void add_row_f16(float* acc, uint4 u) {
    const __half2* hp = (const __half2*)&u;
#pragma unroll
    for (int i = 0; i < 4; ++i) {
        acc[2 * i]     += __half2float(__low2half(hp[i]));
        acc[2 * i + 1] += __half2float(__high2half(hp[i]));
    }
}

// ---------------- P1: LDS-staged counting scatter + parallel gb precompute -------------
__global__ void p1_place(const int* __restrict__ src, const int* __restrict__ dst,
                         const int* __restrict__ batch,
                         int* __restrict__ bcur, unsigned int* __restrict__ ebuf,
                         int* __restrict__ gb) {
    if (blockIdx.x >= NBLK_E) {
        int g = (blockIdx.x - NBLK_E) * 256 + threadIdx.x;
        if (g < NUM_G) {
            int lo = 0, hi = N_NODES;
            while (lo < hi) { int m = (lo + hi) >> 1; if (batch[m] < g) lo = m + 1; else hi = m; }
            gb[g] = lo;
            if (g == NUM_G - 1) gb[NUM_G] = N_NODES;
        }
        return;
    }
    __shared__ int h[NB];
    __shared__ int lbase[NB];
    __shared__ int gbase[NB];
    __shared__ int wsum4[4];
    __shared__ int total_s;
    __shared__ unsigned int stage[P01_EPB];      // 8 KB
    __shared__ unsigned char sbuck[P01_EPB];     // 2 KB
    int tid = threadIdx.x;
    h[tid] = 0;
    __syncthreads();
    unsigned int pk[8]; int bn[8];
    int b0 = blockIdx.x * P01_EPB;
    int e8 = b0 + tid * 8;
    if (e8 + 8 <= N_EDGES) {
        int4 s0 = *(const int4*)(src + e8);
        int4 s1 = *(const int4*)(src + e8 + 4);
        int4 d0 = *(const int4*)(dst + e8);
        int4 d1 = *(const int4*)(dst + e8 + 4);
        int ss[8] = { s0.x, s0.y, s0.z, s0.w, s1.x, s1.y, s1.z, s1.w };
        int dd[8] = { d0.x, d0.y, d0.z, d0.w, d1.x, d1.y, d1.z, d1.w };
#pragma unroll
        for (int k = 0; k < 8; ++k) {
            bn[k] = dd[k] / KPB;
            pk[k] = ((unsigned)ss[k] << 9) | (unsigned)(dd[k] - bn[k] * KPB);
        }
    } else {
#pragma unroll
        for (int k = 0; k < 8; ++k) {
            int e = e8 + k;
            if (e < N_EDGES) {
                int d = dst[e];
                bn[k] = d / KPB;
                pk[k] = ((unsigned)src[e] << 9) | (unsigned)(d - bn[k] * KPB);
            } else bn[k] = -1;
        }
    }
#pragma unroll
    for (int k = 0; k < 8; ++k)
        if (bn[k] >= 0) atomicAdd(&h[bn[k]], 1);
    __syncthreads();
    int c = h[tid];
    gbase[tid] = c ? atomicAdd(&bcur[tid], c) : 0;
    int lane = tid & 63, wv = tid >> 6;
    int sv = c;
#pragma unroll
    for (int off = 1; off < 64; off <<= 1) {
        int n = __shfl_up(sv, off, 64);
        if (lane >= off) sv += n;
    }
    if (lane == 63) wsum4[wv] = sv;
    __syncthreads();
    int woff = 0;
    for (int w = 0; w < wv; ++w) woff += wsum4[w];
    int excl = sv - c + woff;
    lbase[tid] = excl;
    if (tid == NB - 1) total_s = excl + c;
    __syncthreads();
    h[tid] = 0;
    __syncthreads();
#pragma unroll
    for (int k = 0; k < 8; ++k) {
        if (bn[k] >= 0) {
            int r = atomicAdd(&h[bn[k]], 1);
            int p_ = lbase[bn[k]] + r;
            stage[p_] = pk[k];
            sbuck[p_] = (unsigned char)bn[k];
        }
    }
    __syncthreads();
    int total = total_s;
    for (int i = tid; i < total; i += NB) {
        int b = sbuck[i];
        ebuf[(size_t)b * BCAP + gbase[b] + (i - lbase[b])] = stage[i];
    }
}

// ---------------- P2: CSR build with LDS-staged cw (coalesced flush) --------------------
// cw.x = (dstLocal<<17) | src  — agg consumes dstLocal for edge-centric accumulation.
__global__ void p2_build(const unsigned int* __restrict__ ebuf, const int* __restrict__ bcur,
                         const float* __restrict__ x,
                         int* __restrict__ row_ptr, int* __restrict__ deg,
                         uint2* __restrict__ cw,
                         float* __restrict__ dinv, __half* __restrict__ xp) {
    __shared__ int hist[512];
    __shared__ float ldinv[512];
    __shared__ int wsum[8];
    __shared__ int woff[8];
    __shared__ uint2 scw[BCAP];           // 64 KB staging
    int b  = blockIdx.x;
    int t  = threadIdx.x;                 // 0..1023
    int dbase = b * KPB;
    int nd = N_NODES - dbase; if (nd > KPB) nd = KPB;
    if (t < 512) hist[t] = 0;
    __syncthreads();
    int e0 = b * BCAP;
    int e1 = e0 + bcur[b];
    for (int e = e0 + t; e < e1; e += 1024)
        atomicAdd(&hist[ebuf[e] & 511u], 1);
    __syncthreads();
    int v = 0, sv = 0;
    int lane = t & 63, wv = t >> 6;
    if (t < 512) {                        // waves 0..7 (wave-uniform branch)
        v = hist[t];
        sv = v;
#pragma unroll
        for (int off = 1; off < 64; off <<= 1) {
            int n = __shfl_up(sv, off, 64);
            if (lane >= off) sv += n;
        }
        if (lane == 63) wsum[wv] = sv;
    }
    __syncthreads();
    if (t == 0) {
        int run = 0;
#pragma unroll
        for (int w = 0; w < 8; ++w) { woff[w] = run; run += wsum[w]; }
    }
    __syncthreads();
    int excl = 0;
    if (t < 512) {
        excl = sv - v + woff[wv];
        float di = rsqrtf(1.0f + (float)v);
        ldinv[t] = di;
        if (t < nd) {
            row_ptr[dbase + t] = e0 + excl;
            deg[dbase + t]     = v;
            dinv[dbase + t]    = di;
        }
    }
    __syncthreads();
    if (t < 512) hist[t] = excl;          // LOCAL cursor into scw
    __syncthreads();
    for (int e = e0 + t; e < e1; e += 1024) {
        unsigned int w = ebuf[e];
        int dl = (int)(w & 511u);
        int pos = atomicAdd(&hist[dl], 1);
        scw[pos] = make_uint2(((w & 511u) << 17) | (w >> 9), __float_as_uint(ldinv[dl]));
    }
    __syncthreads();
    int cnt_ = e1 - e0;
    for (int i = t; i < cnt_; i += 1024)  // coalesced flush
        cw[e0 + i] = scw[i];
    for (int idx = t; idx < nd * F_PAD; idx += 1024) {
        int vl = idx >> 4, f = idx & 15;
        int gv = dbase + vl;
        xp[(size_t)gv * F_PAD + f] =
            __float2half_rn((f < F_IN) ? ldinv[vl] * x[(size_t)gv * F_IN + f] : 0.f);
    }
}

// ---------------- fused agg_gemm1 (edge-centric) + edge_sort8 ---------------------------
// agg: each thread takes 8 consecutive edges (uniform work — no wave-max-degree
// divergence; 16 independent gathers in flight), accumulates same-dst runs in regs,
// flushes to xs via LDS fp32 atomics on dst change. xs pre-initialized with self-loop.
__global__ void agg_es8(const __half* __restrict__ xp, const int* __restrict__ row_ptr,
                        const int* __restrict__ deg, const uint2* __restrict__ cw,
                        const float* __restrict__ dinv,
                        const float* __restrict__ W1, const float* __restrict__ b1,
                        __half* __restrict__ Bh,
                        const int* __restrict__ gb,
                        uint2* __restrict__ ewp, int* __restrict__ gro) {
    __shared__ union __align__(16) SBuf {
        struct {
            float xs[128][F_PAD];          // 8 KB
            float W1s[F_IN * HID];         // 5.5 KB
            float b1s[HID];
            float ds[128];
        } a;
        struct {
            uint2 dat[GCAP];               // 8 KB
            uint2 ord[GCAP];               // 8 KB
            unsigned char reg[GCAP];       // 1 KB
        } s;
    } sh;
    __shared__ int cnt[NREG];
    __shared__ int cur_s[NREG];
    __shared__ int stot;
    int tid = threadIdx.x;

    if (blockIdx.x < NAGG) {
        // ---------------- stage W1/b1; init xs = self-loop row; ds ----------------------
        for (int i = tid; i < F_IN * HID; i += 256) sh.a.W1s[i] = W1[i];
        if (tid < HID) sh.a.b1s[tid] = b1[tid];
        const uint4* xp4 = (const uint4*)xp;   // row = 2 uint4 (8 halves each)
        int v0   = blockIdx.x * 128;
        int nmax = N_NODES - v0; if (nmax > 128) nmax = 128;
        {
            int n = tid >> 1, half = tid & 1;
            if (n < nmax) {
                float t8[8];
#pragma unroll
                for (int i = 0; i < 8; ++i) t8[i] = 0.f;
                add_row_f16(t8, xp4[(size_t)(v0 + n) * 2 + half]);
#pragma unroll
                for (int i = 0; i < 8; ++i) sh.a.xs[n][half * 8 + i] = t8[i];
            }
        }
        if (tid < nmax) sh.a.ds[tid] = dinv[v0 + tid];
        __syncthreads();
        // ---------------- edge-centric accumulate (per-bucket sub-ranges) ---------------
        int bb0 = v0 / KPB;
        int bb1 = (v0 + nmax - 1) / KPB;
        for (int bb = bb0; bb <= bb1; ++bb) {
            int vlo = v0 > bb * KPB ? v0 : bb * KPB;
            int vhi = v0 + nmax < (bb + 1) * KPB ? v0 + nmax : (bb + 1) * KPB;
            int ee0 = row_ptr[vlo];
            int ee1 = row_ptr[vhi - 1] + deg[vhi - 1];
            int nb0 = bb * KPB - v0;           // dl + nb0 = node index in block
            for (int base = ee0 + tid * 8; base < ee1; base += 2048) {
                int lim = ee1 - base; if (lim > 8) lim = 8;
                float a[16];
#pragma unroll
                for (int k = 0; k < 16; ++k) a[k] = 0.f;
                int cur = -1;
                for (int k = 0; k < lim; ++k) {
                    uint2 q = cw[base + k];
                    int dl  = (int)(q.x >> 17);
                    int s   = (int)(q.x & SRC_MASK);
                    if (dl != cur) {
                        if (cur >= 0) {
                            int nblk = cur + nb0;
#pragma unroll
                            for (int f = 0; f < 16; ++f) {
                                atomicAdd(&sh.a.xs[nblk][f], a[f]);
                                a[f] = 0.f;
                            }
                        }
                        cur = dl;
                    }
                    uint4 u0 = xp4[(size_t)s * 2];
                    uint4 u1 = xp4[(size_t)s * 2 + 1];
                    add_row_f16(a, u0);
                    add_row_f16(a + 8, u1);
                }
                if (cur >= 0) {
                    int nblk = cur + nb0;
#pragma unroll
                    for (int f = 0; f < 16; ++f)
                        atomicAdd(&sh.a.xs[nblk][f], a[f]);
                }
            }
        }
        __syncthreads();
        // ---------------- GEMM phase (b128 xs reads, W1 cols in regs) -------------------
        int jf   = tid & 127;
        int half = tid >> 7;
        float w[F_IN];
#pragma unroll
        for (int k = 0; k < F_IN; ++k) w[k] = sh.a.W1s[k * HID + jf];
        float bb_ = sh.a.b1s[jf];
        for (int n = half; n < nmax; n += 2) {
            const float4* xr = (const float4*)sh.a.xs[n];
            float4 x0 = xr[0], x1 = xr[1], x2 = xr[2];   // 3 broadcast b128 reads
            float acc = x0.x * w[0] + x0.y * w[1] + x0.z * w[2] + x0.w * w[3]
                      + x1.x * w[4] + x1.y * w[5] + x1.z * w[6] + x1.w * w[7]
                      + x2.x * w[8] + x2.y * w[9] + x2.z * w[10];
            float dv = sh.a.ds[n];
            float h = fmaxf(dv * acc + bb_, 0.f);
            Bh[(size_t)(v0 + n) * HID + jf] = __float2half_rn(dv * h);
        }
    } else {
        // ---------------- edge_sort8: single-pass LDS-staged ----------------------------
        int g = blockIdx.x - NAGG;
        if (tid < NREG) cnt[tid] = 0;
        if (tid == 0) stot = 0;
        __syncthreads();
        int r0 = gb[g], r1 = gb[g + 1];
        int bb0 = 0, bb1 = -1;
        if (r1 > r0) { bb0 = r0 / KPB; bb1 = (r1 - 1) / KPB; }
        // stage + count (single global read pass); mask dl out of src
        for (int bb = bb0; bb <= bb1; ++bb) {
            int vlo = r0 > bb * KPB ? r0 : bb * KPB;
            int vhi = r1 < bb * KPB + KPB ? r1 : bb * KPB + KPB;
            int ee0 = row_ptr[vlo];
            int ee1 = row_ptr[vhi - 1] + deg[vhi - 1];
            for (int e = ee0 + tid; e < ee1; e += 256) {
                uint2 q = cw[e];
                unsigned s = q.x & SRC_MASK;
                int rg = (int)(s / REGW);
                int si = atomicAdd(&stot, 1);
                sh.s.dat[si] = make_uint2(s, q.y);
                sh.s.reg[si] = (unsigned char)rg;
                atomicAdd(&cnt[rg], 1);
            }
        }
        for (int v = r0 + tid; v < r1; v += 256) {
            int rg = (int)((unsigned)v / REGW);
            int si = atomicAdd(&stot, 1);
            sh.s.dat[si] = make_uint2((unsigned)v, __float_as_uint(dinv[v]));
            sh.s.reg[si] = (unsigned char)rg;
            atomicAdd(&cnt[rg], 1);
        }
        __syncthreads();
        if (tid == 0) {
            int run = 0;
#pragma unroll
            for (int p = 0; p < NREG; ++p) {
                gro[g * 9 + p] = g * GCAP + run;
                cur_s[p] = run;
                run += cnt[p];
            }
            gro[g * 9 + 8] = g * GCAP + run;
        }
        __syncthreads();
        // order within LDS
        int tot = stot;
        for (int i = tid; i < tot; i += 256) {
            int pos = atomicAdd(&cur_s[sh.s.reg[i]], 1);
            sh.s.ord[pos] = sh.s.dat[i];
        }
        __syncthreads();
        // coalesced flush
        for (int i = tid; i < tot; i += 256)
            ewp[(size_t)g * GCAP + i] = sh.s.ord[i];
    }
}

// ---------------- pool_gather: block (gset,p); 32 groups x 8 lanes; 8 groups/graph ------
__global__ void pool_gather(const __half* __restrict__ Bh,
                            const int* __restrict__ gro,
                            const uint2* __restrict__ ewp,
                            float* __restrict__ part) {
    __shared__ float red[32][HID + 4];    // 16.9 KB
    int b    = blockIdx.x;
    int gset = b >> 3;
    int p    = b & 7;
    int tid  = threadIdx.x;
    int grp  = tid >> 3;                  // 0..31
    int lane = tid & 7;                   // owns feats [8*lane,8*lane+8) and [64+8*lane,..)
    int g    = gset * GPB + (grp >> 3);   // 4 graphs/block
    int q    = grp & 7;                   // eighth
    const uint4* B4 = (const uint4*)Bh;   // row = 16 uint4
    float acc[16];
#pragma unroll
    for (int k = 0; k < 16; ++k) acc[k] = 0.f;

    int e0 = gro[g * 9 + p], e1 = gro[g * 9 + p + 1];
    int e = e0 + q;
    for (; e + 8 < e1; e += 16) {         // 2 entries/iter, 4 row-loads in flight
        uint2 q0 = ewp[e], q1 = ewp[e + 8];
        uint4 u00 = B4[(size_t)q0.x * 16 + lane];
        uint4 u01 = B4[(size_t)q0.x * 16 + 8 + lane];
        uint4 u10 = B4[(size_t)q1.x * 16 + lane];
        uint4 u11 = B4[(size_t)q1.x * 16 + 8 + lane];
        float w0 = __uint_as_float(q0.y), w1 = __uint_as_float(q1.y);
        acc_row_f16(acc,     u00, w0);
        acc_row_f16(acc + 8, u01, w0);
        acc_row_f16(acc,     u10, w1);
        acc_row_f16(acc + 8, u11, w1);
    }
    for (; e < e1; e += 8) {
        uint2 q0 = ewp[e];
        uint4 u00 = B4[(size_t)q0.x * 16 + lane];
        uint4 u01 = B4[(size_t)q0.x * 16 + 8 + lane];
        float w0 = __uint_as_float(q0.y);
        acc_row_f16(acc,     u00, w0);
        acc_row_f16(acc + 8, u01, w0);
    }
    // feature mapping: acc[k] -> feat 8*lane+k ; acc[8+k] -> feat 64+8*lane+k
#pragma unroll
    for (int k = 0; k < 8; ++k) red[grp][lane * 8 + k]      = acc[k];
#pragma unroll
    for (int k = 0; k < 8; ++k) red[grp][64 + lane * 8 + k] = acc[8 + k];
    __syncthreads();
    for (int i = tid; i < GPB * HID; i += 256) {
        int gg = i >> 7, f = i & 127;
        int rb = gg * 8;
        float s = 0.f;
#pragma unroll
        for (int r = 0; r < 8; ++r) s += red[rb + r][f];
        part[(size_t)((gset * GPB + gg) * NREG + p) * HID + f] = s;
    }
}

// ---------------- combine partials + mean + W2 + b2 + head (8 graphs/block) ------------
__global__ void combine_head(const float* __restrict__ part, const int* __restrict__ gb,
                             const float* __restrict__ W2, const float* __restrict__ b2,
                             const float* __restrict__ Wlin, const float* __restrict__ blin,
                             float* __restrict__ out) {
    __shared__ float r[CH_G][HID];
    __shared__ float tt[CH_G][HID + 4];
    __shared__ float bsc[CH_G];
    int g0  = blockIdx.x * CH_G;
    int tid = threadIdx.x;                // 256
    int f   = tid & 127;
    int gh  = tid >> 7;                   // 0..1 -> graphs gh*4..gh*4+3
    int q0  = gh * 4;
#pragma unroll
    for (int c = 0; c < 4; ++c) {
        int gg = q0 + c;
        int g  = g0 + gg;
        float s = 0.f;
#pragma unroll
        for (int p = 0; p < NREG; ++p) s += part[(size_t)(g * NREG + p) * HID + f];
        int cnt = gb[g + 1] - gb[g];
        float inv = (cnt > 0) ? 1.0f / (float)cnt : 0.f;
        r[gg][f] = s * inv;
        if (f == 0) bsc[gg] = (cnt > 0) ? 1.0f : 0.f;
    }
    __syncthreads();
    float bf = b2[f];
    float t0 = bf * bsc[q0];
    float t1 = bf * bsc[q0 + 1];
    float t2 = bf * bsc[q0 + 2];
    float t3 = bf * bsc[q0 + 3];
#pragma unroll 4
    for (int k = 0; k < HID; ++k) {
        float w = W2[k * HID + f];
        t0 += r[q0][k] * w;
        t1 += r[q0 + 1][k] * w;
        t2 += r[q0 + 2][k] * w;
        t3 += r[q0 + 3][k] * w;
    }
    tt[q0][f]     = t0;
    tt[q0 + 1][f] = t1;
    tt[q0 + 2][f] = t2;
    tt[q0 + 3][f] = t3;
    __syncthreads();
    if (tid < CH_G * F_OUT) {             // 152 threads
        int gg = tid / F_OUT;
        int fo = tid - gg * F_OUT;
        float o = blin[fo];
#pragma unroll 8
        for (int k = 0; k < HID; ++k) o += tt[gg][k] * Wlin[k * F_OUT + fo];
        out[(size_t)(g0 + gg) * F_OUT + fo] = o;
    }
}

extern "C" void kernel_launch(void* const* d_in, const int* in_sizes, int n_in,
                              void* d_out, int out_size, void* d_ws, size_t ws_size,
                              hipStream_t stream) {
    const float* x    = (const float*)d_in[0];
    const int*   esrc = (const int*)  d_in[1];
    const int*   edst = (const int*)  d_in[2];
    const int*   batch= (const int*)  d_in[3];
    const float* W1   = (const float*)d_in[4];
    const float* b1   = (const float*)d_in[5];
    const float* W2   = (const float*)d_in[6];
    const float* b2   = (const float*)d_in[7];
    const float* Wlin = (const float*)d_in[8];
    const float* blin = (const float*)d_in[9];
    float* out = (float*)d_out;

    // workspace layout (~106 MB), 16B-aligned segments
    char* p = (char*)d_ws;
    float*        dinv    = (float*)p;        p += sizeof(float) * N_NODES;
    __half*       xp      = (__half*)p;       p += sizeof(__half) * (size_t)N_NODES * F_PAD;
    __half*       Bh      = (__half*)p;       p += sizeof(__half) * (size_t)N_NODES * HID;
    unsigned int* ebuf    = (unsigned int*)p; p += sizeof(unsigned int) * (size_t)NB * BCAP;
    uint2*        cw      = (uint2*)p;        p += sizeof(uint2) * (size_t)NB * BCAP;
    int*          deg     = (int*)p;          p += sizeof(int) * N_NODES;
    uint2*        ewp     = (uint2*)p;        p += sizeof(uint2) * (size_t)NUM_G * GCAP;
    float*        part    = (float*)p;        p += sizeof(float) * (size_t)NUM_G * NREG * HID;
    int*          row_ptr = (int*)p;          p += sizeof(int) * (N_NODES + 4);
    int*          gb      = (int*)p;          p += sizeof(int) * (NUM_G + 4);
    int*          gro     = (int*)p;          p += sizeof(int) * (NUM_G * 9 + 4);
    int*          bcur    = (int*)p;          p += sizeof(int) * NB;

    hipMemsetAsync(bcur, 0, sizeof(int) * NB, stream);
    // edge bucket-scatter + gb precompute (independent block ranges, one launch)
    p1_place<<<NBLK_E + NGBB, 256, 0, stream>>>(esrc, edst, batch, bcur, ebuf, gb);
    p2_build<<<NB, 1024, 0, stream>>>(ebuf, bcur, x, row_ptr, deg, cw, dinv, xp);

    agg_es8<<<NAGG + NUM_G, 256, 0, stream>>>(xp, row_ptr, deg, cw, dinv, W1, b1, Bh,
                                              gb, ewp, gro);

    pool_gather<<<(NUM_G / GPB) * NREG, 256, 0, stream>>>(Bh, gro, ewp, part);

    combine_head<<<NUM_G / CH_G, 256, 0, stream>>>(part, gb, W2, b2, Wlin, blin, out);
}

// Round 12
// 202.603 us; speedup vs baseline: 1.1367x; 1.1367x over previous
//
#include <hip/hip_runtime.h>
#include <hip/hip_fp16.h>

#define N_NODES 100000
#define N_EDGES 1600000
#define NUM_G   4096
#define HID     128
#define F_IN    11
#define F_PAD   16
#define F_OUT   19

#define NB      256                  // dst buckets
#define KPB     391                  // nodes per bucket: 256*391 = 100096 >= 100000
#define BCAP    8192                 // padded capacity per bucket (max count ~6600)
#define GCAP    1024                 // padded ewp capacity per graph (max ~790)
#define P01_EPB 2048                 // edges per block in P1
#define NBLK_E  782                  // edge blocks in P1 = ceil(1.6M/2048)
#define NGBB    16                   // gb blocks in P1 (16*256 = 4096 graphs)
#define NREG    8                    // src regions (XCD shards)
#define REGW    12500                // nodes per region
#define GPB     4                    // graphs per pool_gather block (8 groups/graph)
#define NAGG    782                  // agg blocks = ceil(100000/128)
#define CH_G    8                    // graphs per combine_head block

// ---------------- helpers ----------------
__device__ inline void acc_row_f16(float* acc, uint4 u, float w) {
    const __half2* hp = (const __half2*)&u;
#pragma unroll
    for (int i = 0; i < 4; ++i) {
        acc[2 * i]     += __half2float(__low2half(hp[i]))  * w;
        acc[2 * i + 1] += __half2float(__high2half(hp[i])) * w;
    }
}
__device__ inline void add_row_f16(float* acc, uint4 u) {
    const __half2* hp = (const __half2*)&u;
#pragma unroll
    for (int i = 0; i < 4; ++i) {
        acc[2 * i]     += __half2float(__low2half(hp[i]));
        acc[2 * i + 1] += __half2float(__high2half(hp[i]));
    }
}

// ---------------- P1: LDS-staged counting scatter + parallel gb precompute -------------
__global__ void p1_place(const int* __restrict__ src, const int* __restrict__ dst,
                         const int* __restrict__ batch,
                         int* __restrict__ bcur, unsigned int* __restrict__ ebuf,
                         int* __restrict__ gb) {
    if (blockIdx.x >= NBLK_E) {
        int g = (blockIdx.x - NBLK_E) * 256 + threadIdx.x;
        if (g < NUM_G) {
            int lo = 0, hi = N_NODES;
            while (lo < hi) { int m = (lo + hi) >> 1; if (batch[m] < g) lo = m + 1; else hi = m; }
            gb[g] = lo;
            if (g == NUM_G - 1) gb[NUM_G] = N_NODES;
        }
        return;
    }
    __shared__ int h[NB];
    __shared__ int lbase[NB];
    __shared__ int gbase[NB];
    __shared__ int wsum4[4];
    __shared__ int total_s;
    __shared__ unsigned int stage[P01_EPB];      // 8 KB
    __shared__ unsigned char sbuck[P01_EPB];     // 2 KB
    int tid = threadIdx.x;
    h[tid] = 0;
    __syncthreads();
    unsigned int pk[8]; int bn[8];
    int b0 = blockIdx.x * P01_EPB;
    int e8 = b0 + tid * 8;
    if (e8 + 8 <= N_EDGES) {
        int4 s0 = *(const int4*)(src + e8);
        int4 s1 = *(const int4*)(src + e8 + 4);
        int4 d0 = *(const int4*)(dst + e8);
        int4 d1 = *(const int4*)(dst + e8 + 4);
        int ss[8] = { s0.x, s0.y, s0.z, s0.w, s1.x, s1.y, s1.z, s1.w };
        int dd[8] = { d0.x, d0.y, d0.z, d0.w, d1.x, d1.y, d1.z, d1.w };
#pragma unroll
        for (int k = 0; k < 8; ++k) {
            bn[k] = dd[k] / KPB;
            pk[k] = ((unsigned)ss[k] << 9) | (unsigned)(dd[k] - bn[k] * KPB);
        }
    } else {
#pragma unroll
        for (int k = 0; k < 8; ++k) {
            int e = e8 + k;
            if (e < N_EDGES) {
                int d = dst[e];
                bn[k] = d / KPB;
                pk[k] = ((unsigned)src[e] << 9) | (unsigned)(d - bn[k] * KPB);
            } else bn[k] = -1;
        }
    }
#pragma unroll
    for (int k = 0; k < 8; ++k)
        if (bn[k] >= 0) atomicAdd(&h[bn[k]], 1);
    __syncthreads();
    int c = h[tid];
    gbase[tid] = c ? atomicAdd(&bcur[tid], c) : 0;
    int lane = tid & 63, wv = tid >> 6;
    int sv = c;
#pragma unroll
    for (int off = 1; off < 64; off <<= 1) {
        int n = __shfl_up(sv, off, 64);
        if (lane >= off) sv += n;
    }
    if (lane == 63) wsum4[wv] = sv;
    __syncthreads();
    int woff = 0;
    for (int w = 0; w < wv; ++w) woff += wsum4[w];
    int excl = sv - c + woff;
    lbase[tid] = excl;
    if (tid == NB - 1) total_s = excl + c;
    __syncthreads();
    h[tid] = 0;
    __syncthreads();
#pragma unroll
    for (int k = 0; k < 8; ++k) {
        if (bn[k] >= 0) {
            int r = atomicAdd(&h[bn[k]], 1);
            int p_ = lbase[bn[k]] + r;
            stage[p_] = pk[k];
            sbuck[p_] = (unsigned char)bn[k];
        }
    }
    __syncthreads();
    int total = total_s;
    for (int i = tid; i < total; i += NB) {
        int b = sbuck[i];
        ebuf[(size_t)b * BCAP + gbase[b] + (i - lbase[b])] = stage[i];
    }
}

// ---------------- P2: CSR build with LDS-staged cw (coalesced flush) --------------------
__global__ void p2_build(const unsigned int* __restrict__ ebuf, const int* __restrict__ bcur,
                         const float* __restrict__ x,
                         int* __restrict__ row_ptr, int* __restrict__ deg,
                         uint2* __restrict__ cw,
                         float* __restrict__ dinv, __half* __restrict__ xp) {
    __shared__ int hist[512];
    __shared__ float ldinv[512];
    __shared__ int wsum[8];
    __shared__ int woff[8];
    __shared__ uint2 scw[BCAP];           // 64 KB staging
    int b  = blockIdx.x;
    int t  = threadIdx.x;                 // 0..1023
    int dbase = b * KPB;
    int nd = N_NODES - dbase; if (nd > KPB) nd = KPB;
    if (t < 512) hist[t] = 0;
    __syncthreads();
    int e0 = b * BCAP;
    int e1 = e0 + bcur[b];
    for (int e = e0 + t; e < e1; e += 1024)
        atomicAdd(&hist[ebuf[e] & 511u], 1);
    __syncthreads();
    int v = 0, sv = 0;
    int lane = t & 63, wv = t >> 6;
    if (t < 512) {                        // waves 0..7 (wave-uniform branch)
        v = hist[t];
        sv = v;
#pragma unroll
        for (int off = 1; off < 64; off <<= 1) {
            int n = __shfl_up(sv, off, 64);
            if (lane >= off) sv += n;
        }
        if (lane == 63) wsum[wv] = sv;
    }
    __syncthreads();
    if (t == 0) {
        int run = 0;
#pragma unroll
        for (int w = 0; w < 8; ++w) { woff[w] = run; run += wsum[w]; }
    }
    __syncthreads();
    int excl = 0;
    if (t < 512) {
        excl = sv - v + woff[wv];
        float di = rsqrtf(1.0f + (float)v);
        ldinv[t] = di;
        if (t < nd) {
            row_ptr[dbase + t] = e0 + excl;
            deg[dbase + t]     = v;
            dinv[dbase + t]    = di;
        }
    }
    __syncthreads();
    if (t < 512) hist[t] = excl;          // LOCAL cursor into scw
    __syncthreads();
    for (int e = e0 + t; e < e1; e += 1024) {
        unsigned int w = ebuf[e];
        int dl = (int)(w & 511u);
        int pos = atomicAdd(&hist[dl], 1);
        scw[pos] = make_uint2(w >> 9, __float_as_uint(ldinv[dl]));
    }
    __syncthreads();
    int cnt_ = e1 - e0;
    for (int i = t; i < cnt_; i += 1024)  // coalesced flush
        cw[e0 + i] = scw[i];
    for (int idx = t; idx < nd * F_PAD; idx += 1024) {
        int vl = idx >> 4, f = idx & 15;
        int gv = dbase + vl;
        xp[(size_t)gv * F_PAD + f] =
            __float2half_rn((f < F_IN) ? ldinv[vl] * x[(size_t)gv * F_IN + f] : 0.f);
    }
}

// ---------------- fused agg_gemm1 + edge_sort8 ------------------------------------------
__global__ void agg_es8(const __half* __restrict__ xp, const int* __restrict__ row_ptr,
                        const int* __restrict__ deg, const uint2* __restrict__ cw,
                        const float* __restrict__ dinv,
                        const float* __restrict__ W1, const float* __restrict__ b1,
                        __half* __restrict__ Bh,
                        const int* __restrict__ gb,
                        uint2* __restrict__ ewp, int* __restrict__ gro) {
    __shared__ union SBuf {
        struct {
            float xs[128][F_PAD];          // 8 KB
            float W1s[F_IN * HID];         // 5.5 KB
            float b1s[HID];
            float ds[128];
        } a;
        struct {
            uint2 dat[GCAP];               // 8 KB
            uint2 ord[GCAP];               // 8 KB
            unsigned char reg[GCAP];       // 1 KB
        } s;
    } sh;
    __shared__ int cnt[NREG];
    __shared__ int cur[NREG];
    __shared__ int stot;
    int tid = threadIdx.x;

    if (blockIdx.x < NAGG) {
        // ---------------- agg_gemm1 body ----------------
        for (int i = tid; i < F_IN * HID; i += 256) sh.a.W1s[i] = W1[i];
        if (tid < HID) sh.a.b1s[tid] = b1[tid];
        const uint4* xp4 = (const uint4*)xp;   // row = 2 uint4 (8 halves each)
        int v0   = blockIdx.x * 128;
        int v    = v0 + (tid >> 1);
        int lane = tid & 1;                    // lane owns 8 feats
        if (v < N_NODES) {
            if (lane == 0) sh.a.ds[tid >> 1] = dinv[v];
            float a[8];
#pragma unroll
            for (int k = 0; k < 8; ++k) a[k] = 0.f;
            add_row_f16(a, xp4[(size_t)v * 2 + lane]);         // self-loop
            int j = row_ptr[v], end = j + deg[v];
            for (; j + 3 < end; j += 4) {
                int s0 = cw[j].x, s1 = cw[j + 1].x, s2 = cw[j + 2].x, s3 = cw[j + 3].x;
                uint4 u0 = xp4[(size_t)s0 * 2 + lane];
                uint4 u1 = xp4[(size_t)s1 * 2 + lane];
                uint4 u2 = xp4[(size_t)s2 * 2 + lane];
                uint4 u3 = xp4[(size_t)s3 * 2 + lane];
                add_row_f16(a, u0); add_row_f16(a, u1);
                add_row_f16(a, u2); add_row_f16(a, u3);
            }
            for (; j < end; ++j)
                add_row_f16(a, xp4[(size_t)cw[j].x * 2 + lane]);
#pragma unroll
            for (int k = 0; k < 8; ++k) sh.a.xs[tid >> 1][lane * 8 + k] = a[k];
        }
        __syncthreads();
        int jf   = tid & 127;
        int half = tid >> 7;
        float w[F_IN];
#pragma unroll
        for (int k = 0; k < F_IN; ++k) w[k] = sh.a.W1s[k * HID + jf];
        float bb = sh.a.b1s[jf];
        int nmax = N_NODES - v0; if (nmax > 128) nmax = 128;
        for (int n = half; n < nmax; n += 2) {
            const float4* xr = (const float4*)sh.a.xs[n];
            float4 x0 = xr[0], x1 = xr[1], x2 = xr[2];   // 3 broadcast b128 reads
            float a = x0.x * w[0] + x0.y * w[1] + x0.z * w[2] + x0.w * w[3]
                    + x1.x * w[4] + x1.y * w[5] + x1.z * w[6] + x1.w * w[7]
                    + x2.x * w[8] + x2.y * w[9] + x2.z * w[10];
            float dv = sh.a.ds[n];
            float h = fmaxf(dv * a + bb, 0.f);
            Bh[(size_t)(v0 + n) * HID + jf] = __float2half_rn(dv * h);
        }
    } else {
        // ---------------- edge_sort8: single-pass LDS-staged ----------------------------
        int g = blockIdx.x - NAGG;
        if (tid < NREG) cnt[tid] = 0;
        if (tid == 0) stot = 0;
        __syncthreads();
        int r0 = gb[g], r1 = gb[g + 1];
        int bb0 = 0, bb1 = -1;
        if (r1 > r0) { bb0 = r0 / KPB; bb1 = (r1 - 1) / KPB; }
        // stage + count (single global read pass)
        for (int bb = bb0; bb <= bb1; ++bb) {
            int vlo = r0 > bb * KPB ? r0 : bb * KPB;
            int vhi = r1 < bb * KPB + KPB ? r1 : bb * KPB + KPB;
            int ee0 = row_ptr[vlo];
            int ee1 = row_ptr[vhi - 1] + deg[vhi - 1];
            for (int e = ee0 + tid; e < ee1; e += 256) {
                uint2 q = cw[e];
                int rg = (int)(q.x / REGW);
                int si = atomicAdd(&stot, 1);
                sh.s.dat[si] = q;
                sh.s.reg[si] = (unsigned char)rg;
                atomicAdd(&cnt[rg], 1);
            }
        }
        for (int v = r0 + tid; v < r1; v += 256) {
            int rg = (int)((unsigned)v / REGW);
            int si = atomicAdd(&stot, 1);
            sh.s.dat[si] = make_uint2((unsigned)v, __float_as_uint(dinv[v]));
            sh.s.reg[si] = (unsigned char)rg;
            atomicAdd(&cnt[rg], 1);
        }
        __syncthreads();
        if (tid == 0) {
            int run = 0;
#pragma unroll
            for (int p = 0; p < NREG; ++p) {
                gro[g * 9 + p] = g * GCAP + run;
                cur[p] = run;
                run += cnt[p];
            }
            gro[g * 9 + 8] = g * GCAP + run;
        }
        __syncthreads();
        // order within LDS
        int tot = stot;
        for (int i = tid; i < tot; i += 256) {
            int pos = atomicAdd(&cur[sh.s.reg[i]], 1);
            sh.s.ord[pos] = sh.s.dat[i];
        }
        __syncthreads();
        // coalesced flush
        for (int i = tid; i < tot; i += 256)
            ewp[(size_t)g * GCAP + i] = sh.s.ord[i];
    }
}

// ---------------- pool_gather: block (gset,p); 32 groups x 8 lanes; 8 groups/graph ------
__global__ void pool_gather(const __half* __restrict__ Bh,
                            const int* __restrict__ gro,
                            const uint2* __restrict__ ewp,
                            float* __restrict__ part) {
    __shared__ float red[32][HID + 4];    // 16.9 KB
    int b    = blockIdx.x;
    int gset = b >> 3;
    int p    = b & 7;
    int tid  = threadIdx.x;
    int grp  = tid >> 3;                  // 0..31
    int lane = tid & 7;                   // owns feats [8*lane,8*lane+8) and [64+8*lane,..)
    int g    = gset * GPB + (grp >> 3);   // 4 graphs/block
    int q    = grp & 7;                   // eighth
    const uint4* B4 = (const uint4*)Bh;   // row = 16 uint4
    float acc[16];
#pragma unroll
    for (int k = 0; k < 16; ++k) acc[k] = 0.f;

    int e0 = gro[g * 9 + p], e1 = gro[g * 9 + p + 1];
    int e = e0 + q;
    for (; e + 8 < e1; e += 16) {         // 2 entries/iter, 4 row-loads in flight
        uint2 q0 = ewp[e], q1 = ewp[e + 8];
        uint4 u00 = B4[(size_t)q0.x * 16 + lane];
        uint4 u01 = B4[(size_t)q0.x * 16 + 8 + lane];
        uint4 u10 = B4[(size_t)q1.x * 16 + lane];
        uint4 u11 = B4[(size_t)q1.x * 16 + 8 + lane];
        float w0 = __uint_as_float(q0.y), w1 = __uint_as_float(q1.y);
        acc_row_f16(acc,     u00, w0);
        acc_row_f16(acc + 8, u01, w0);
        acc_row_f16(acc,     u10, w1);
        acc_row_f16(acc + 8, u11, w1);
    }
    for (; e < e1; e += 8) {
        uint2 q0 = ewp[e];
        uint4 u00 = B4[(size_t)q0.x * 16 + lane];
        uint4 u01 = B4[(size_t)q0.x * 16 + 8 + lane];
        float w0 = __uint_as_float(q0.y);
        acc_row_f16(acc,     u00, w0);
        acc_row_f16(acc + 8, u01, w0);
    }
    // feature mapping: acc[k] -> feat 8*lane+k ; acc[8+k] -> feat 64+8*lane+k
#pragma unroll
    for (int k = 0; k < 8; ++k) red[grp][lane * 8 + k]      = acc[k];
#pragma unroll
    for (int k = 0; k < 8; ++k) red[grp][64 + lane * 8 + k] = acc[8 + k];
    __syncthreads();
    for (int i = tid; i < GPB * HID; i += 256) {
        int gg = i >> 7, f = i & 127;
        int rb = gg * 8;
        float s = 0.f;
#pragma unroll
        for (int r = 0; r < 8; ++r) s += red[rb + r][f];
        part[(size_t)((gset * GPB + gg) * NREG + p) * HID + f] = s;
    }
}

// ---------------- combine partials + mean + W2 + b2 + head (8 graphs/block) ------------
__global__ void combine_head(const float* __restrict__ part, const int* __restrict__ gb,
                             const float* __restrict__ W2, const float* __restrict__ b2,
                             const float* __restrict__ Wlin, const float* __restrict__ blin,
                             float* __restrict__ out) {
    __shared__ float r[CH_G][HID];
    __shared__ float tt[CH_G][HID + 4];
    __shared__ float bsc[CH_G];
    int g0  = blockIdx.x * CH_G;
    int tid = threadIdx.x;                // 256
    int f   = tid & 127;
    int gh  = tid >> 7;                   // 0..1 -> graphs gh*4..gh*4+3
    int q0  = gh * 4;
#pragma unroll
    for (int c = 0; c < 4; ++c) {
        int gg = q0 + c;
        int g  = g0 + gg;
        float s = 0.f;
#pragma unroll
        for (int p = 0; p < NREG; ++p) s += part[(size_t)(g * NREG + p) * HID + f];
        int cnt = gb[g + 1] - gb[g];
        float inv = (cnt > 0) ? 1.0f / (float)cnt : 0.f;
        r[gg][f] = s * inv;
        if (f == 0) bsc[gg] = (cnt > 0) ? 1.0f : 0.f;
    }
    __syncthreads();
    float bf = b2[f];
    float t0 = bf * bsc[q0];
    float t1 = bf * bsc[q0 + 1];
    float t2 = bf * bsc[q0 + 2];
    float t3 = bf * bsc[q0 + 3];
#pragma unroll 4
    for (int k = 0; k < HID; ++k) {
        float w = W2[k * HID + f];
        t0 += r[q0][k] * w;
        t1 += r[q0 + 1][k] * w;
        t2 += r[q0 + 2][k] * w;
        t3 += r[q0 + 3][k] * w;
    }
    tt[q0][f]     = t0;
    tt[q0 + 1][f] = t1;
    tt[q0 + 2][f] = t2;
    tt[q0 + 3][f] = t3;
    __syncthreads();
    if (tid < CH_G * F_OUT) {             // 152 threads
        int gg = tid / F_OUT;
        int fo = tid - gg * F_OUT;
        float o = blin[fo];
#pragma unroll 8
        for (int k = 0; k < HID; ++k) o += tt[gg][k] * Wlin[k * F_OUT + fo];
        out[(size_t)(g0 + gg) * F_OUT + fo] = o;
    }
}

extern "C" void kernel_launch(void* const* d_in, const int* in_sizes, int n_in,
                              void* d_out, int out_size, void* d_ws, size_t ws_size,
                              hipStream_t stream) {
    const float* x    = (const float*)d_in[0];
    const int*   esrc = (const int*)  d_in[1];
    const int*   edst = (const int*)  d_in[2];
    const int*   batch= (const int*)  d_in[3];
    const float* W1   = (const float*)d_in[4];
    const float* b1   = (const float*)d_in[5];
    const float* W2   = (const float*)d_in[6];
    const float* b2   = (const float*)d_in[7];
    const float* Wlin = (const float*)d_in[8];
    const float* blin = (const float*)d_in[9];
    float* out = (float*)d_out;

    // workspace layout (~106 MB), 16B-aligned segments
    char* p = (char*)d_ws;
    float*        dinv    = (float*)p;        p += sizeof(float) * N_NODES;
    __half*       xp      = (__half*)p;       p += sizeof(__half) * (size_t)N_NODES * F_PAD;
    __half*       Bh      = (__half*)p;       p += sizeof(__half) * (size_t)N_NODES * HID;
    unsigned int* ebuf    = (unsigned int*)p; p += sizeof(unsigned int) * (size_t)NB * BCAP;
    uint2*        cw      = (uint2*)p;        p += sizeof(uint2) * (size_t)NB * BCAP;
    int*          deg     = (int*)p;          p += sizeof(int) * N_NODES;
    uint2*        ewp     = (uint2*)p;        p += sizeof(uint2) * (size_t)NUM_G * GCAP;
    float*        part    = (float*)p;        p += sizeof(float) * (size_t)NUM_G * NREG * HID;
    int*          row_ptr = (int*)p;          p += sizeof(int) * (N_NODES + 4);
    int*          gb      = (int*)p;          p += sizeof(int) * (NUM_G + 4);
    int*          gro     = (int*)p;          p += sizeof(int) * (NUM_G * 9 + 4);
    int*          bcur    = (int*)p;          p += sizeof(int) * NB;

    hipMemsetAsync(bcur, 0, sizeof(int) * NB, stream);
    // edge bucket-scatter + gb precompute (independent block ranges, one launch)
    p1_place<<<NBLK_E + NGBB, 256, 0, stream>>>(esrc, edst, batch, bcur, ebuf, gb);
    p2_build<<<NB, 1024, 0, stream>>>(ebuf, bcur, x, row_ptr, deg, cw, dinv, xp);

    agg_es8<<<NAGG + NUM_G, 256, 0, stream>>>(xp, row_ptr, deg, cw, dinv, W1, b1, Bh,
                                              gb, ewp, gro);

    pool_gather<<<(NUM_G / GPB) * NREG, 256, 0, stream>>>(Bh, gro, ewp, part);

    combine_head<<<NUM_G / CH_G, 256, 0, stream>>>(part, gb, W2, b2, Wlin, blin, out);
}